// Round 2
// baseline (263.084 us; speedup 1.0000x reference)
//
#include <hip/hip_runtime.h>

#define BB 32
#define AA 8400
#define GG 100
#define CC 80
#define KK 10

// ---------------------------------------------------------------------------
// Kernel 1: one block per (b,g). Compute align over all anchors, take top-10,
// scatter matched winners into packed-argmax and norm buffers with atomics.
// ---------------------------------------------------------------------------
__global__ __launch_bounds__(256) void topk_assign(
    const float* __restrict__ scores,      // (B,A,C)
    const float* __restrict__ dbox,        // (B,A,4)
    const float* __restrict__ anchors,     // (A,2)
    const int*   __restrict__ gt_labels,   // (B,G)
    const float* __restrict__ gt_bboxes,   // (B,G,4)
    const int*   __restrict__ gt_mask,     // (B,G)
    unsigned long long* __restrict__ packed, // (B,A) argmax carrier
    unsigned int* __restrict__ normb)        // (B,A) float bits
{
    const int bg = blockIdx.x;
    const int b = bg / GG;
    const int g = bg % GG;
    if (gt_mask[bg] == 0) return;

    const float4 gt = reinterpret_cast<const float4*>(gt_bboxes)[bg];
    const float area_g = (gt.z - gt.x) * (gt.w - gt.y);
    const int label = gt_labels[bg];
    const int tid = threadIdx.x;

    float vals[KK];
    float ovs[KK];
    int   idxs[KK];
#pragma unroll
    for (int i = 0; i < KK; ++i) { vals[i] = -1.0f; ovs[i] = 0.0f; idxs[i] = -1; }

    const float4* db = reinterpret_cast<const float4*>(dbox) + (size_t)b * AA;
    const float*  sc = scores + (size_t)b * AA * CC + label;
    const float2* an = reinterpret_cast<const float2*>(anchors);

    for (int a = tid; a < AA; a += 256) {
        float2 pt = an[a];
        // strict in-box test on anchor center
        if (!(pt.x > gt.x && pt.x < gt.z && pt.y > gt.y && pt.y < gt.w)) continue;
        float4 p = db[a];
        float lx = fmaxf(gt.x, p.x), ly = fmaxf(gt.y, p.y);
        float rx = fminf(gt.z, p.z), ry = fminf(gt.w, p.w);
        float w = fmaxf(rx - lx, 0.0f), h = fmaxf(ry - ly, 0.0f);
        float inter = w * h;
        float area_p = (p.z - p.x) * (p.w - p.y);
        float iou = inter / (area_g + area_p - inter + 1e-9f);
        if (iou <= 0.0f) continue;
        float s = sc[(size_t)a * CC];
        float i2 = iou * iou;
        float align = sqrtf(s) * (i2 * i2 * i2);
        if (align <= 0.0f) continue;
        if (align > vals[KK - 1]) {
            int j = KK - 1;
            while (j > 0 && vals[j - 1] < align) {
                vals[j] = vals[j - 1]; ovs[j] = ovs[j - 1]; idxs[j] = idxs[j - 1];
                --j;
            }
            vals[j] = align; ovs[j] = iou; idxs[j] = a;
        }
    }

    // Block-wide extraction of global top-10 from 256 per-thread sorted lists.
    __shared__ float rv[256];
    __shared__ int   rt[256];
    __shared__ float wv[KK], wov[KK];
    __shared__ int   wa[KK];
    int ptr = 0;
    for (int r = 0; r < KK; ++r) {
        rv[tid] = (ptr < KK) ? vals[ptr] : -1.0f;
        rt[tid] = tid;
        __syncthreads();
        for (int s = 128; s > 0; s >>= 1) {
            if (tid < s) {
                float o = rv[tid + s];
                if (o > rv[tid]) { rv[tid] = o; rt[tid] = rt[tid + s]; }
            }
            __syncthreads();
        }
        if (tid == 0) wv[r] = rv[0];
        if (tid == rt[0] && ptr < KK) {
            wov[r] = ovs[ptr];
            wa[r]  = idxs[ptr];
            ++ptr;
        }
        __syncthreads();
    }

    __shared__ float s_maxov, s_maxal;
    if (tid == 0) {
        float ma = (wv[0] > 0.0f) ? wv[0] : 0.0f;  // max_align = top-1 (if matched)
        float mo = 0.0f;
        for (int r = 0; r < KK; ++r)
            if (wv[r] > 0.0f) mo = fmaxf(mo, wov[r]);
        s_maxal = ma; s_maxov = mo;
    }
    __syncthreads();

    if (tid < KK && wv[tid] > 0.0f) {
        int a = wa[tid];
        float nval = wv[tid] * s_maxov / (s_maxal + 1e-9f);
        atomicMax(&normb[(size_t)b * AA + a], __float_as_uint(nval));
        unsigned long long pk =
            ((unsigned long long)__float_as_uint(wov[tid]) << 32) |
            (unsigned long long)(0xFFFFFFFFu - (unsigned)g);  // smaller g wins ties
        atomicMax(&packed[(size_t)b * AA + a], pk);
    }
}

// ---------------------------------------------------------------------------
// Kernel 2: per anchor — decode argmax, write bbox_labels (float4), fg, cls.
// ---------------------------------------------------------------------------
__global__ __launch_bounds__(256) void finalize_anchor(
    const float* __restrict__ gt_bboxes,
    const int*   __restrict__ gt_labels,
    const unsigned long long* __restrict__ packed,
    float* __restrict__ out_bbox,   // (B,A,4)
    float* __restrict__ out_fg,     // (B,A)
    int*   __restrict__ cls_ws)     // (B,A)
{
    int i = blockIdx.x * blockDim.x + threadIdx.x;
    if (i >= BB * AA) return;
    int b = i / AA;
    unsigned long long p = packed[i];
    bool fg = (p != 0ULL);
    float4 bb = make_float4(-1.0f, -1.0f, -1.0f, -1.0f);
    int cls = -1;
    if (fg) {
        int g = (int)(0xFFFFFFFFu - (unsigned)(p & 0xFFFFFFFFull));
        bb  = reinterpret_cast<const float4*>(gt_bboxes)[b * GG + g];
        cls = gt_labels[b * GG + g];
    }
    reinterpret_cast<float4*>(out_bbox)[i] = bb;
    out_fg[i] = fg ? 1.0f : 0.0f;
    cls_ws[i] = cls;
}

// ---------------------------------------------------------------------------
// Kernel 3: per (anchor, class) — one-hot * norm, fully coalesced stores.
// ---------------------------------------------------------------------------
__global__ __launch_bounds__(256) void finalize_cls(
    const int* __restrict__ cls_ws,
    const unsigned int* __restrict__ normb,
    float* __restrict__ out_cls)    // (B,A,C)
{
    int t = blockIdx.x * blockDim.x + threadIdx.x;
    if (t >= BB * AA * CC) return;
    int ba = t / CC;
    int c  = t - ba * CC;
    float v = (c == cls_ws[ba]) ? __uint_as_float(normb[ba]) : 0.0f;
    out_cls[t] = v;
}

extern "C" void kernel_launch(void* const* d_in, const int* in_sizes, int n_in,
                              void* d_out, int out_size, void* d_ws, size_t ws_size,
                              hipStream_t stream) {
    const float* scores    = (const float*)d_in[0];
    const float* dbox      = (const float*)d_in[1];
    const float* anchors   = (const float*)d_in[2];
    const int*   gt_labels = (const int*)d_in[3];
    const float* gt_bboxes = (const float*)d_in[4];
    const int*   gt_mask   = (const int*)d_in[5];

    float* out = (float*)d_out;
    float* out_bbox = out;                              // B*A*4
    float* out_cls  = out + (size_t)BB * AA * 4;        // B*A*C
    float* out_fg   = out + (size_t)BB * AA * (4 + CC); // B*A

    const size_t N = (size_t)BB * AA;
    unsigned long long* packed = (unsigned long long*)d_ws;
    unsigned int* normb = (unsigned int*)((char*)d_ws + N * 8);
    int* cls_ws = (int*)((char*)d_ws + N * 12);

    // zero the atomic carriers (ws is poisoned to 0xAA before every launch)
    hipMemsetAsync(d_ws, 0, N * 12, stream);

    topk_assign<<<BB * GG, 256, 0, stream>>>(scores, dbox, anchors, gt_labels,
                                             gt_bboxes, gt_mask, packed, normb);
    finalize_anchor<<<(int)((N + 255) / 256), 256, 0, stream>>>(
        gt_bboxes, gt_labels, packed, out_bbox, out_fg, cls_ws);
    finalize_cls<<<(int)((N * CC + 255) / 256), 256, 0, stream>>>(
        cls_ws, normb, out_cls);
}

// Round 4
// 182.387 us; speedup vs baseline: 1.4424x; 1.4424x over previous
//
#include <hip/hip_runtime.h>

#define BB 32
#define AA 8400
#define GG 100
#define CC 80
#define KK 10
#define MAXC 1024   // proven bound: ≤ 25^2 + 13^2 + 7^2 = 843 in-box anchors

// ---------------------------------------------------------------------------
// Kernel 1: one block per (b,g). In-box anchors come from closed-form grid
// ranges (3 scales), candidates land dense in LDS, top-10 via shfl reduction.
// ---------------------------------------------------------------------------
__global__ __launch_bounds__(256) void topk_assign(
    const float* __restrict__ scores,      // (B,A,C)
    const float* __restrict__ dbox,        // (B,A,4)
    const int*   __restrict__ gt_labels,   // (B,G)
    const float* __restrict__ gt_bboxes,   // (B,G,4)
    const int*   __restrict__ gt_mask,     // (B,G)
    unsigned long long* __restrict__ packed, // (B,A) argmax carrier
    unsigned int* __restrict__ normb)        // (B,A) float bits
{
    const int bg = blockIdx.x;
    const int b = bg / GG;
    const int g = bg - b * GG;
    if (gt_mask[bg] == 0) return;

    const float4 gt = reinterpret_cast<const float4*>(gt_bboxes)[bg];
    const int label = gt_labels[bg];
    const int tid = threadIdx.x;

    // Closed-form strict in-box ranges per scale. anchor x = (ix+0.5)*s.
    // x > x0  <=>  ix > x0/s - 0.5  ;  x < x1  <=>  ix < x1/s - 0.5.
    // s is a power of two so x/s is exact, and u-0.5 is exact in fp32 here,
    // so boundary semantics match the reference bit-exactly.
    int ix0_0, iy0_0, cx0, cy0, cnt0;
    int ix0_1, iy0_1, cx1, cy1, cnt1;
    int ix0_2, iy0_2, cx2, cy2, cnt2;
    {
        // scale 8, n=80
        int xl = max((int)floorf(gt.x * 0.125f - 0.5f) + 1, 0);
        int xh = min((int)ceilf (gt.z * 0.125f - 0.5f) - 1, 79);
        int yl = max((int)floorf(gt.y * 0.125f - 0.5f) + 1, 0);
        int yh = min((int)ceilf (gt.w * 0.125f - 0.5f) - 1, 79);
        ix0_0 = xl; iy0_0 = yl;
        cx0 = max(xh - xl + 1, 0); cy0 = max(yh - yl + 1, 0);
        cnt0 = cx0 * cy0;
    }
    {
        // scale 16, n=40
        int xl = max((int)floorf(gt.x * 0.0625f - 0.5f) + 1, 0);
        int xh = min((int)ceilf (gt.z * 0.0625f - 0.5f) - 1, 39);
        int yl = max((int)floorf(gt.y * 0.0625f - 0.5f) + 1, 0);
        int yh = min((int)ceilf (gt.w * 0.0625f - 0.5f) - 1, 39);
        ix0_1 = xl; iy0_1 = yl;
        cx1 = max(xh - xl + 1, 0); cy1 = max(yh - yl + 1, 0);
        cnt1 = cx1 * cy1;
    }
    {
        // scale 32, n=20
        int xl = max((int)floorf(gt.x * 0.03125f - 0.5f) + 1, 0);
        int xh = min((int)ceilf (gt.z * 0.03125f - 0.5f) - 1, 19);
        int yl = max((int)floorf(gt.y * 0.03125f - 0.5f) + 1, 0);
        int yh = min((int)ceilf (gt.w * 0.03125f - 0.5f) - 1, 19);
        ix0_2 = xl; iy0_2 = yl;
        cx2 = max(xh - xl + 1, 0); cy2 = max(yh - yl + 1, 0);
        cnt2 = cx2 * cy2;
    }
    int total = cnt0 + cnt1 + cnt2;
    if (total > MAXC) total = MAXC;   // unreachable (bound 843), insurance only
    if (total == 0) return;

    __shared__ float c_align[MAXC];
    __shared__ float c_iou[MAXC];
    __shared__ int   c_a[MAXC];
    __shared__ float wv[KK], wov[KK];
    __shared__ int   wa[KK];
    __shared__ unsigned long long wred[4];
    __shared__ float s_stats[2];

    if (tid < KK) wv[tid] = 0.0f;

    const float area_g = (gt.z - gt.x) * (gt.w - gt.y);
    const float4* db = reinterpret_cast<const float4*>(dbox) + (size_t)b * AA;
    const float*  sc = scores + (size_t)b * AA * CC + label;

    for (int t = tid; t < total; t += 256) {
        int u = t, a;
        if (u < cnt0) {
            int ty = u / cx0; int tx = u - ty * cx0;
            a = (iy0_0 + ty) * 80 + (ix0_0 + tx);
        } else {
            u -= cnt0;
            if (u < cnt1) {
                int ty = u / cx1; int tx = u - ty * cx1;
                a = 6400 + (iy0_1 + ty) * 40 + (ix0_1 + tx);
            } else {
                u -= cnt1;
                int ty = u / cx2; int tx = u - ty * cx2;
                a = 8000 + (iy0_2 + ty) * 20 + (ix0_2 + tx);
            }
        }
        float4 p = db[a];
        float lx = fmaxf(gt.x, p.x), ly = fmaxf(gt.y, p.y);
        float rx = fminf(gt.z, p.z), ry = fminf(gt.w, p.w);
        float w = fmaxf(rx - lx, 0.0f), h = fmaxf(ry - ly, 0.0f);
        float inter = w * h;
        float area_p = (p.z - p.x) * (p.w - p.y);
        float iou = inter / (area_g + area_p - inter + 1e-9f);
        float s = sc[(size_t)a * CC];
        float i2 = iou * iou;
        c_align[t] = sqrtf(s) * (i2 * i2 * i2);
        c_iou[t]   = iou;
        c_a[t]     = a;
    }
    __syncthreads();

    // Top-10: per-thread scan + wave shfl-max + 4-way combine. 2 barriers/round.
    for (int r = 0; r < KK; ++r) {
        float best = 0.0f; int bslot = -1;
        for (int i = tid; i < total; i += 256) {
            float v = c_align[i];
            if (v > best) { best = v; bslot = i; }
        }
        unsigned long long pk =
            ((unsigned long long)__float_as_uint(best) << 32) | (unsigned)bslot;
#pragma unroll
        for (int off = 32; off > 0; off >>= 1) {
            unsigned long long o = __shfl_xor(pk, off);
            if (o > pk) pk = o;
        }
        if ((tid & 63) == 0) wred[tid >> 6] = pk;
        __syncthreads();
        if (tid == 0) {
            unsigned long long m = wred[0];
            if (wred[1] > m) m = wred[1];
            if (wred[2] > m) m = wred[2];
            if (wred[3] > m) m = wred[3];
            float bv = __uint_as_float((unsigned)(m >> 32));
            int slot = (int)(unsigned)m;
            if (bv > 0.0f && slot >= 0) {
                wv[r] = bv; wov[r] = c_iou[slot]; wa[r] = c_a[slot];
                c_align[slot] = -1.0f;   // exclude from later rounds
            } else {
                wv[r] = 0.0f;
            }
        }
        __syncthreads();
        if (wv[r] <= 0.0f) break;   // uniform decision
    }

    if (tid == 0) {
        float mo = 0.0f;
#pragma unroll
        for (int r = 0; r < KK; ++r)
            if (wv[r] > 0.0f) mo = fmaxf(mo, wov[r]);
        s_stats[0] = mo;        // max_ov over matched
        s_stats[1] = wv[0];     // max_align (round-0 winner is the global max)
    }
    __syncthreads();

    if (tid < KK && wv[tid] > 0.0f) {
        int a = wa[tid];
        float nval = wv[tid] * s_stats[0] / (s_stats[1] + 1e-9f);
        atomicMax(&normb[(size_t)b * AA + a], __float_as_uint(nval));
        unsigned long long pk =
            ((unsigned long long)__float_as_uint(wov[tid]) << 32) |
            (unsigned long long)(0xFFFFFFFFu - (unsigned)g);  // smaller g wins ties
        atomicMax(&packed[(size_t)b * AA + a], pk);
    }
}

// ---------------------------------------------------------------------------
// Kernel 2: per anchor — decode argmax, write bbox_labels (float4), fg, cls.
// ---------------------------------------------------------------------------
__global__ __launch_bounds__(256) void finalize_anchor(
    const float* __restrict__ gt_bboxes,
    const int*   __restrict__ gt_labels,
    const unsigned long long* __restrict__ packed,
    float* __restrict__ out_bbox,   // (B,A,4)
    float* __restrict__ out_fg,     // (B,A)
    int*   __restrict__ cls_ws)     // (B,A)
{
    int i = blockIdx.x * blockDim.x + threadIdx.x;
    if (i >= BB * AA) return;
    int b = i / AA;
    unsigned long long p = packed[i];
    bool fg = (p != 0ULL);
    float4 bb = make_float4(-1.0f, -1.0f, -1.0f, -1.0f);
    int cls = -1;
    if (fg) {
        int g = (int)(0xFFFFFFFFu - (unsigned)(p & 0xFFFFFFFFull));
        bb  = reinterpret_cast<const float4*>(gt_bboxes)[b * GG + g];
        cls = gt_labels[b * GG + g];
    }
    reinterpret_cast<float4*>(out_bbox)[i] = bb;
    out_fg[i] = fg ? 1.0f : 0.0f;
    cls_ws[i] = cls;
}

// ---------------------------------------------------------------------------
// Kernel 3: per (anchor, 4 classes) — one-hot * norm, float4 coalesced stores.
// ---------------------------------------------------------------------------
__global__ __launch_bounds__(256) void finalize_cls(
    const int* __restrict__ cls_ws,
    const unsigned int* __restrict__ normb,
    float4* __restrict__ out_cls4)  // (B,A,C/4)
{
    int t = blockIdx.x * blockDim.x + threadIdx.x;
    if (t >= BB * AA * (CC / 4)) return;
    int ba = t / (CC / 4);
    int q  = t - ba * (CC / 4);
    int rel = cls_ws[ba] - q * 4;
    float4 v = make_float4(0.0f, 0.0f, 0.0f, 0.0f);
    if (rel >= 0 && rel < 4) {
        float nv = __uint_as_float(normb[ba]);
        if      (rel == 0) v.x = nv;
        else if (rel == 1) v.y = nv;
        else if (rel == 2) v.z = nv;
        else               v.w = nv;
    }
    out_cls4[t] = v;
}

extern "C" void kernel_launch(void* const* d_in, const int* in_sizes, int n_in,
                              void* d_out, int out_size, void* d_ws, size_t ws_size,
                              hipStream_t stream) {
    const float* scores    = (const float*)d_in[0];
    const float* dbox      = (const float*)d_in[1];
    // d_in[2] (anchors) no longer needed: grid is closed-form
    const int*   gt_labels = (const int*)d_in[3];
    const float* gt_bboxes = (const float*)d_in[4];
    const int*   gt_mask   = (const int*)d_in[5];

    float* out = (float*)d_out;
    float* out_bbox = out;                              // B*A*4
    float* out_cls  = out + (size_t)BB * AA * 4;        // B*A*C
    float* out_fg   = out + (size_t)BB * AA * (4 + CC); // B*A

    const size_t N = (size_t)BB * AA;
    unsigned long long* packed = (unsigned long long*)d_ws;
    unsigned int* normb = (unsigned int*)((char*)d_ws + N * 8);
    int* cls_ws = (int*)((char*)d_ws + N * 12);

    // zero the atomic carriers (ws is poisoned to 0xAA before every launch)
    hipMemsetAsync(d_ws, 0, N * 12, stream);

    topk_assign<<<BB * GG, 256, 0, stream>>>(scores, dbox, gt_labels,
                                             gt_bboxes, gt_mask, packed, normb);
    finalize_anchor<<<(int)((N + 255) / 256), 256, 0, stream>>>(
        gt_bboxes, gt_labels, packed, out_bbox, out_fg, cls_ws);
    finalize_cls<<<(int)((N * (CC / 4) + 255) / 256), 256, 0, stream>>>(
        cls_ws, normb, (float4*)out_cls);
}

// Round 6
// 179.746 us; speedup vs baseline: 1.4636x; 1.0147x over previous
//
#include <hip/hip_runtime.h>

#define BB 32
#define AA 8400
#define GG 100
#define CC 80
#define KK 10
#define MAXC 1024   // proven bound: ≤ 25^2 + 13^2 + 7^2 = 843 in-box anchors

// ---------------------------------------------------------------------------
// Kernel 1: one block per (b,g). In-box anchors via closed-form grid ranges,
// candidates dense in LDS, top-10 selected entirely inside wave 0 with zero
// barriers (per-lane 16-entry register cache + 16-bit used-mask + shfl max).
// ---------------------------------------------------------------------------
__global__ __launch_bounds__(256) void topk_assign(
    const float* __restrict__ scores,      // (B,A,C)
    const float* __restrict__ dbox,        // (B,A,4)
    const int*   __restrict__ gt_labels,   // (B,G)
    const float* __restrict__ gt_bboxes,   // (B,G,4)
    const int*   __restrict__ gt_mask,     // (B,G)
    unsigned long long* __restrict__ packed, // (B,A) argmax carrier
    unsigned int* __restrict__ normb)        // (B,A) float bits
{
    const int bg = blockIdx.x;
    const int b = bg / GG;
    const int g = bg - b * GG;
    if (gt_mask[bg] == 0) return;

    const float4 gt = reinterpret_cast<const float4*>(gt_bboxes)[bg];
    const int label = gt_labels[bg];
    const int tid = threadIdx.x;

    // Closed-form strict in-box ranges per scale. anchor x = (ix+0.5)*s.
    // x > x0  <=>  ix > x0/s - 0.5 ;  x < x1  <=>  ix < x1/s - 0.5.
    // s is 2^k so x/s is exact, u-0.5 exact in fp32 here -> bit-exact bounds.
    int ix0_0, iy0_0, cx0, cnt0;
    int ix0_1, iy0_1, cx1, cnt1;
    int ix0_2, iy0_2, cx2, cnt2;
    {
        int xl = max((int)floorf(gt.x * 0.125f - 0.5f) + 1, 0);
        int xh = min((int)ceilf (gt.z * 0.125f - 0.5f) - 1, 79);
        int yl = max((int)floorf(gt.y * 0.125f - 0.5f) + 1, 0);
        int yh = min((int)ceilf (gt.w * 0.125f - 0.5f) - 1, 79);
        ix0_0 = xl; iy0_0 = yl;
        cx0 = max(xh - xl + 1, 0);
        cnt0 = cx0 * max(yh - yl + 1, 0);
    }
    {
        int xl = max((int)floorf(gt.x * 0.0625f - 0.5f) + 1, 0);
        int xh = min((int)ceilf (gt.z * 0.0625f - 0.5f) - 1, 39);
        int yl = max((int)floorf(gt.y * 0.0625f - 0.5f) + 1, 0);
        int yh = min((int)ceilf (gt.w * 0.0625f - 0.5f) - 1, 39);
        ix0_1 = xl; iy0_1 = yl;
        cx1 = max(xh - xl + 1, 0);
        cnt1 = cx1 * max(yh - yl + 1, 0);
    }
    {
        int xl = max((int)floorf(gt.x * 0.03125f - 0.5f) + 1, 0);
        int xh = min((int)ceilf (gt.z * 0.03125f - 0.5f) - 1, 19);
        int yl = max((int)floorf(gt.y * 0.03125f - 0.5f) + 1, 0);
        int yh = min((int)ceilf (gt.w * 0.03125f - 0.5f) - 1, 19);
        ix0_2 = xl; iy0_2 = yl;
        cx2 = max(xh - xl + 1, 0);
        cnt2 = cx2 * max(yh - yl + 1, 0);
    }
    int total = cnt0 + cnt1 + cnt2;
    if (total > MAXC) total = MAXC;   // unreachable (bound 843), insurance only
    if (total == 0) return;

    __shared__ float c_align[MAXC];
    __shared__ float c_iou[MAXC];
    __shared__ int   c_a[MAXC];

    const float area_g = (gt.z - gt.x) * (gt.w - gt.y);
    const float4* db = reinterpret_cast<const float4*>(dbox) + (size_t)b * AA;
    const float*  sc = scores + (size_t)b * AA * CC + label;

    for (int t = tid; t < total; t += 256) {
        int u = t, a;
        if (u < cnt0) {
            int ty = u / cx0; int tx = u - ty * cx0;
            a = (iy0_0 + ty) * 80 + (ix0_0 + tx);
        } else {
            u -= cnt0;
            if (u < cnt1) {
                int ty = u / cx1; int tx = u - ty * cx1;
                a = 6400 + (iy0_1 + ty) * 40 + (ix0_1 + tx);
            } else {
                u -= cnt1;
                int ty = u / cx2; int tx = u - ty * cx2;
                a = 8000 + (iy0_2 + ty) * 20 + (ix0_2 + tx);
            }
        }
        float4 p = db[a];
        float lx = fmaxf(gt.x, p.x), ly = fmaxf(gt.y, p.y);
        float rx = fminf(gt.z, p.z), ry = fminf(gt.w, p.w);
        float w = fmaxf(rx - lx, 0.0f), h = fmaxf(ry - ly, 0.0f);
        float inter = w * h;
        float area_p = (p.z - p.x) * (p.w - p.y);
        float iou = inter / (area_g + area_p - inter + 1e-9f);
        float s = sc[(size_t)a * CC];
        float i2 = iou * iou;
        c_align[t] = sqrtf(s) * (i2 * i2 * i2);
        c_iou[t]   = iou;
        c_a[t]     = a;
    }
    __syncthreads();
    if (tid >= 64) return;   // waves 1..3 done; wave 0 selects with no barriers

    const int lane = tid;
    float av[16];
#pragma unroll
    for (int i = 0; i < 16; ++i) {
        int slot = lane + 64 * i;
        av[i] = (slot < total) ? c_align[slot] : -1.0f;
    }

    unsigned used = 0;
    float win_v = 0.0f;
    int   win_slot = 0;
    for (int r = 0; r < KK; ++r) {
        float best = 0.0f; int bi = 0; bool any = false;
#pragma unroll
        for (int i = 0; i < 16; ++i) {
            bool ok = (((used >> i) & 1u) == 0u) && (av[i] > best);
            best = ok ? av[i] : best;
            bi   = ok ? i : bi;
            any  = any || ok;
        }
        unsigned slotenc = any ? (unsigned)(lane + (bi << 6)) : 0u;
        unsigned long long pk =
            ((unsigned long long)__float_as_uint(best) << 32) | slotenc;
#pragma unroll
        for (int off = 32; off > 0; off >>= 1) {
            unsigned long long o = __shfl_xor(pk, off);
            if (o > pk) pk = o;
        }
        float bv = __uint_as_float((unsigned)(pk >> 32));
        if (bv <= 0.0f) break;                  // wave-uniform: no more winners
        int slot = (int)(pk & 0x3FFull);
        if (lane == r) { win_v = bv; win_slot = slot; }
        if (lane == (slot & 63)) used |= (1u << (slot >> 6));
    }

    bool valid = (lane < KK) && (win_v > 0.0f);
    float myiou = valid ? c_iou[win_slot] : 0.0f;
    float mo = myiou;
#pragma unroll
    for (int off = 32; off > 0; off >>= 1)
        mo = fmaxf(mo, __shfl_xor(mo, off));
    float ma = __shfl(win_v, 0);                // global max align (round 0)
    if (valid) {
        int a = c_a[win_slot];
        float nval = win_v * mo / (ma + 1e-9f);
        atomicMax(&normb[(size_t)b * AA + a], __float_as_uint(nval));
        unsigned long long pk2 =
            ((unsigned long long)__float_as_uint(myiou) << 32) |
            (unsigned long long)(0xFFFFFFFFu - (unsigned)g); // smaller g wins ties
        atomicMax(&packed[(size_t)b * AA + a], pk2);
    }
}

// ---------------------------------------------------------------------------
// Kernel 2 (fused): 20 threads per anchor. All lanes write one float4 of the
// one-hot*norm class row; the q==0 lane also writes bbox (float4) and fg.
// ---------------------------------------------------------------------------
__global__ __launch_bounds__(256) void finalize_all(
    const float* __restrict__ gt_bboxes,
    const int*   __restrict__ gt_labels,
    const unsigned long long* __restrict__ packed,
    const unsigned int* __restrict__ normb,
    float4* __restrict__ out_bbox4,  // (B*A)
    float4* __restrict__ out_cls4,   // (B*A*20)
    float*  __restrict__ out_fg)     // (B*A)
{
    int t = blockIdx.x * blockDim.x + threadIdx.x;
    if (t >= BB * AA * (CC / 4)) return;
    int ba = t / (CC / 4);
    int q  = t - ba * (CC / 4);
    int b  = ba / AA;

    unsigned long long p = packed[ba];
    bool fg = (p != 0ULL);
    int gidx = fg ? (b * GG + (int)(0xFFFFFFFFu - (unsigned)(p & 0xFFFFFFFFull)))
                  : 0;
    int cls = fg ? gt_labels[gidx] : -1;

    float4 v = make_float4(0.0f, 0.0f, 0.0f, 0.0f);
    int rel = cls - q * 4;
    if (rel >= 0 && rel < 4) {
        float nv = __uint_as_float(normb[ba]);
        if      (rel == 0) v.x = nv;
        else if (rel == 1) v.y = nv;
        else if (rel == 2) v.z = nv;
        else               v.w = nv;
    }
    out_cls4[t] = v;

    if (q == 0) {
        float4 bb = fg ? reinterpret_cast<const float4*>(gt_bboxes)[gidx]
                       : make_float4(-1.0f, -1.0f, -1.0f, -1.0f);
        out_bbox4[ba] = bb;
        out_fg[ba] = fg ? 1.0f : 0.0f;
    }
}

extern "C" void kernel_launch(void* const* d_in, const int* in_sizes, int n_in,
                              void* d_out, int out_size, void* d_ws, size_t ws_size,
                              hipStream_t stream) {
    const float* scores    = (const float*)d_in[0];
    const float* dbox      = (const float*)d_in[1];
    // d_in[2] (anchors) not needed: grid is closed-form
    const int*   gt_labels = (const int*)d_in[3];
    const float* gt_bboxes = (const float*)d_in[4];
    const int*   gt_mask   = (const int*)d_in[5];

    float* out = (float*)d_out;
    float* out_bbox = out;                              // B*A*4
    float* out_cls  = out + (size_t)BB * AA * 4;        // B*A*C
    float* out_fg   = out + (size_t)BB * AA * (4 + CC); // B*A

    const size_t N = (size_t)BB * AA;
    unsigned long long* packed = (unsigned long long*)d_ws;
    unsigned int* normb = (unsigned int*)((char*)d_ws + N * 8);

    // zero the atomic carriers (ws is poisoned to 0xAA before every launch)
    hipMemsetAsync(d_ws, 0, N * 12, stream);

    topk_assign<<<BB * GG, 256, 0, stream>>>(scores, dbox, gt_labels,
                                             gt_bboxes, gt_mask, packed, normb);
    finalize_all<<<(int)((N * (CC / 4) + 255) / 256), 256, 0, stream>>>(
        gt_bboxes, gt_labels, packed, normb,
        (float4*)out_bbox, (float4*)out_cls, out_fg);
}